// Round 1
// baseline (138.270 us; speedup 1.0000x reference)
//
#include <hip/hip_runtime.h>
#include <hip/hip_bf16.h>
#include <math.h>

#define B_   8
#define C_   192
#define N_   3136
#define K_   9
#define OUT_ 384
#define G_   4
#define CG_  96   // in-channels per group (2C/G)
#define OG_  96   // out-channels per group

typedef __attribute__((ext_vector_type(8))) short short8;
typedef __attribute__((ext_vector_type(4))) float floatx4;

// ---------------- ws layout (bytes) ----------------
// xT  : B*N*C   bf16 =  9,633,792
// xc  : B*N*2C  bf16 = 19,267,584
// y   : B*OUT*N bf16 = 19,267,584
// Wb  : OUT*CG  bf16 =     73,728
// st  : OUT*2   f32  =      3,072
static const size_t OFF_XT = 0;
static const size_t OFF_XC = 9633792;
static const size_t OFF_Y  = OFF_XC + 19267584;          // 28,901,376
static const size_t OFF_W  = OFF_Y  + 19267584;          // 48,168,960
static const size_t OFF_ST = OFF_W  + 73728;             // 48,242,688

// ---- Kernel S: convert conv weights to bf16, zero BN accumulators ----
__global__ void k_setup(const float* __restrict__ w,
                        __hip_bfloat16* __restrict__ wb,
                        float* __restrict__ st) {
    int i = blockIdx.x * 256 + threadIdx.x;
    if (i < OUT_ * CG_) wb[i] = __float2bfloat16(w[i]);
    if (i < OUT_ * 2)   st[i] = 0.0f;
}

// ---- Kernel A: transpose x [B,C,N] f32 -> xT [B,N,C] bf16 ----
__global__ __launch_bounds__(256) void k_transpose(const float* __restrict__ x,
                                                   __hip_bfloat16* __restrict__ xT) {
    __shared__ float tile[64][65];
    int b  = blockIdx.x;
    int cb = blockIdx.y * 64;
    int nb = blockIdx.z * 64;
    int tid = threadIdx.x;
    int tn  = tid & 63;      // n within tile (read phase)
    int tc4 = tid >> 6;      // 0..3
    const float* xp = x + ((size_t)b * C_ + cb) * N_ + nb;
    #pragma unroll
    for (int i = 0; i < 16; ++i) {
        int c = tc4 + i * 4;
        tile[c][tn] = xp[(size_t)c * N_ + tn];
    }
    __syncthreads();
    __hip_bfloat16* xo = xT + ((size_t)b * N_ + nb) * C_ + cb;
    int tcl = tid & 63;      // c within tile (write phase)
    int tn4 = tid >> 6;
    #pragma unroll
    for (int i = 0; i < 16; ++i) {
        int n = tn4 + i * 4;
        xo[(size_t)n * C_ + tcl] = __float2bfloat16(tile[tcl][n]);
    }
}

// ---- Kernel B: gather neighbors + max-relative, build interleaved xc [B,N,2C] bf16 ----
__global__ __launch_bounds__(256) void k_gather(const __hip_bfloat16* __restrict__ xT,
                                                const int* __restrict__ eidx,
                                                __hip_bfloat16* __restrict__ xc) {
    int b    = blockIdx.x;
    int lane = threadIdx.x & 63;
    int wid  = threadIdx.x >> 6;
    int n    = blockIdx.y * 4 + wid;

    const int* e0 = eidx + ((size_t)b * N_ + n) * K_;                       // x_j idx
    const int* e1 = eidx + (size_t)B_ * N_ * K_ + ((size_t)b * N_ + n) * K_; // x_i idx
    int j0[K_], j1[K_];
    #pragma unroll
    for (int k = 0; k < K_; ++k) { j0[k] = e0[k]; j1[k] = e1[k]; }

    const __hip_bfloat16* xb = xT + (size_t)b * N_ * C_;
    const __hip_bfloat16* xn = xb + (size_t)n * C_;
    __hip_bfloat16* outrow = xc + ((size_t)b * N_ + n) * (2 * C_);

    #pragma unroll
    for (int ch = 0; ch < 3; ++ch) {
        int c = ch * 64 + lane;
        float center = __bfloat162float(xn[c]);
        float rel = -INFINITY;
        #pragma unroll
        for (int k = 0; k < K_; ++k) {
            float xj = __bfloat162float(xb[(size_t)j0[k] * C_ + c]);
            float xi = __bfloat162float(xb[(size_t)j1[k] * C_ + c]);
            rel = fmaxf(rel, xj - xi);
        }
        __hip_bfloat162 pr;
        pr.x = __float2bfloat16(center);
        pr.y = __float2bfloat16(rel);
        reinterpret_cast<__hip_bfloat162*>(outrow)[c] = pr;
    }
}

// ---- Kernel C: grouped 1x1 conv via bf16 MFMA; y [B,OUT,N] bf16 ----
// Per wave: A = W_g (M=96 oc), B = xc 16-col n-tile (K=96), 18 MFMAs.
__global__ __launch_bounds__(256) void k_conv(const __hip_bfloat16* __restrict__ xc,
                                              const __hip_bfloat16* __restrict__ Wb,
                                              const float* __restrict__ bias,
                                              __hip_bfloat16* __restrict__ y) {
    int b  = blockIdx.x;
    int g  = blockIdx.y;
    int nt = blockIdx.z;
    int lane = threadIdx.x & 63;
    int wid  = threadIdx.x >> 6;
    int n0   = nt * 64 + wid * 16;
    int col  = lane & 15;
    int quad = lane >> 4;

    const short* Wp = reinterpret_cast<const short*>(Wb);
    short8 wf[3][6];
    #pragma unroll
    for (int mt = 0; mt < 6; ++mt)
        #pragma unroll
        for (int kc = 0; kc < 3; ++kc)
            wf[kc][mt] = *reinterpret_cast<const short8*>(
                Wp + ((size_t)(g * OG_ + mt * 16 + col) * CG_ + kc * 32 + quad * 8));

    const short* Xp = reinterpret_cast<const short*>(xc);
    size_t rowbase = ((size_t)b * N_ + n0 + col) * (2 * C_) + (size_t)g * CG_;
    short8 bfr[3];
    #pragma unroll
    for (int kc = 0; kc < 3; ++kc)
        bfr[kc] = *reinterpret_cast<const short8*>(Xp + rowbase + kc * 32 + quad * 8);

    floatx4 acc[6];
    #pragma unroll
    for (int mt = 0; mt < 6; ++mt) acc[mt] = (floatx4){0.f, 0.f, 0.f, 0.f};
    #pragma unroll
    for (int kc = 0; kc < 3; ++kc)
        #pragma unroll
        for (int mt = 0; mt < 6; ++mt)
            acc[mt] = __builtin_amdgcn_mfma_f32_16x16x32_bf16(wf[kc][mt], bfr[kc], acc[mt], 0, 0, 0);

    // D layout: col(N=n) = lane&15, row(M=oc) = quad*4 + reg
    #pragma unroll
    for (int mt = 0; mt < 6; ++mt) {
        int ocl = mt * 16 + quad * 4;
        #pragma unroll
        for (int r = 0; r < 4; ++r) {
            int oc = g * OG_ + ocl + r;
            float v = acc[mt][r] + bias[oc];
            y[((size_t)b * OUT_ + oc) * N_ + n0 + col] = __float2bfloat16(v);
        }
    }
}

// ---- Kernel D: per-channel sum / sumsq over (B,N) ----
__global__ __launch_bounds__(256) void k_stats(const __hip_bfloat16* __restrict__ y,
                                               float* __restrict__ st) {
    int oc = blockIdx.x;
    int chunk = blockIdx.y;   // 0..3, each covers 2 batches
    float s = 0.f, ss = 0.f;
    for (int b = chunk * 2; b < chunk * 2 + 2; ++b) {
        const unsigned int* row =
            reinterpret_cast<const unsigned int*>(y + ((size_t)b * OUT_ + oc) * N_);
        for (int i = threadIdx.x; i < N_ / 2; i += 256) {
            unsigned int u = row[i];
            __hip_bfloat162 v = *reinterpret_cast<__hip_bfloat162*>(&u);
            float a0 = __bfloat162float(v.x);
            float a1 = __bfloat162float(v.y);
            s  += a0 + a1;
            ss += a0 * a0 + a1 * a1;
        }
    }
    #pragma unroll
    for (int off = 32; off; off >>= 1) {
        s  += __shfl_down(s, off);
        ss += __shfl_down(ss, off);
    }
    __shared__ float ls[4], lss[4];
    int wid = threadIdx.x >> 6, lane = threadIdx.x & 63;
    if (lane == 0) { ls[wid] = s; lss[wid] = ss; }
    __syncthreads();
    if (threadIdx.x == 0) {
        float S = ls[0] + ls[1] + ls[2] + ls[3];
        float SS = lss[0] + lss[1] + lss[2] + lss[3];
        atomicAdd(&st[oc], S);
        atomicAdd(&st[OUT_ + oc], SS);
    }
}

// ---- Kernel E: BN (batch stats) + exact GELU, write fp32 out [B,OUT,N] ----
__global__ __launch_bounds__(256) void k_bn_gelu(const __hip_bfloat16* __restrict__ y,
                                                 const float* __restrict__ st,
                                                 const float* __restrict__ gamma,
                                                 const float* __restrict__ beta,
                                                 float* __restrict__ out) {
    size_t base = ((size_t)blockIdx.x * 256 + threadIdx.x) * 4;
    if (base >= (size_t)B_ * OUT_ * N_) return;
    int oc = (int)((base / N_) % OUT_);
    const float invM = 1.0f / (float)(B_ * N_);
    float s = st[oc], ss = st[OUT_ + oc];
    float mean = s * invM;
    float var  = ss * invM - mean * mean;
    float inv  = 1.0f / sqrtf(var + 1e-5f);
    float sc = gamma[oc] * inv;
    float sh = beta[oc] - mean * sc;

    const __hip_bfloat162* yp = reinterpret_cast<const __hip_bfloat162*>(y + base);
    __hip_bfloat162 p0 = yp[0], p1 = yp[1];
    float v[4] = { __bfloat162float(p0.x), __bfloat162float(p0.y),
                   __bfloat162float(p1.x), __bfloat162float(p1.y) };
    float4 o;
    float* op = &o.x;
    #pragma unroll
    for (int j = 0; j < 4; ++j) {
        float t = v[j] * sc + sh;
        op[j] = 0.5f * t * (1.0f + erff(t * 0.70710678118654752f));
    }
    *reinterpret_cast<float4*>(out + base) = o;
}

extern "C" void kernel_launch(void* const* d_in, const int* in_sizes, int n_in,
                              void* d_out, int out_size, void* d_ws, size_t ws_size,
                              hipStream_t stream) {
    const float* x      = (const float*)d_in[0];
    const int*   eidx   = (const int*)d_in[1];
    const float* conv_w = (const float*)d_in[2];
    const float* conv_b = (const float*)d_in[3];
    const float* gamma  = (const float*)d_in[4];
    const float* beta   = (const float*)d_in[5];
    float* out = (float*)d_out;

    char* ws = (char*)d_ws;
    __hip_bfloat16* xT = (__hip_bfloat16*)(ws + OFF_XT);
    __hip_bfloat16* xc = (__hip_bfloat16*)(ws + OFF_XC);
    __hip_bfloat16* y  = (__hip_bfloat16*)(ws + OFF_Y);
    __hip_bfloat16* Wb = (__hip_bfloat16*)(ws + OFF_W);
    float*          st = (float*)(ws + OFF_ST);

    // setup: W -> bf16, zero stats
    k_setup<<<144, 256, 0, stream>>>(conv_w, Wb, st);
    // transpose x -> [B,N,C] bf16
    k_transpose<<<dim3(B_, C_ / 64, N_ / 64), 256, 0, stream>>>(x, xT);
    // gather + max-relative -> xc [B,N,2C] bf16
    k_gather<<<dim3(B_, N_ / 4), 256, 0, stream>>>(xT, eidx, xc);
    // grouped conv via MFMA -> y [B,OUT,N] bf16
    k_conv<<<dim3(B_, G_, N_ / 64), 256, 0, stream>>>(xc, Wb, conv_b, y);
    // BN statistics
    k_stats<<<dim3(OUT_, 4), 256, 0, stream>>>(y, st);
    // BN + GELU -> out fp32
    k_bn_gelu<<<dim3((B_ * OUT_ * N_) / (256 * 4)), 256, 0, stream>>>(y, st, gamma, beta, out);
}